// Round 1
// baseline (415.793 us; speedup 1.0000x reference)
//
#include <hip/hip_runtime.h>

// Problem constants (from reference)
#define BB 4
#define CC 256
#define XX 256
#define YY 256
#define NCELLS (BB * XX * YY)   // 262144 cells, 1 MiB of int32

// ---------------------------------------------------------------------------
// Kernel 1: fill the cell->row index grid with -1 (int4-vectorized, coalesced)
// ---------------------------------------------------------------------------
__global__ void k_fill_idx(int4* __restrict__ idx4) {
    int i = blockIdx.x * blockDim.x + threadIdx.x;   // NCELLS/4 threads exactly
    idx4[i] = make_int4(-1, -1, -1, -1);
}

// ---------------------------------------------------------------------------
// Kernel 2: scatter row index n into idx[cell]  (coords unique => no races)
// ---------------------------------------------------------------------------
__global__ void k_scatter_idx(const int* __restrict__ coords,
                              int* __restrict__ idx, int n) {
    int i = blockIdx.x * blockDim.x + threadIdx.x;
    if (i >= n) return;
    int b = coords[i * 3 + 0];
    int x = coords[i * 3 + 1];
    int y = coords[i * 3 + 2];
    // mode="drop": out-of-range coords are dropped
    if ((unsigned)b < BB && (unsigned)x < XX && (unsigned)y < YY) {
        idx[(b * XX + x) * YY + y] = i;
    }
}

// ---------------------------------------------------------------------------
// Kernel 3: gather-style dense write. Block = (b,x) slice; thread = y.
// Each thread owns one output column (all 256 c for its (b,x,y) cell):
//  - reads its feats row in float4 chunks (consecutive c4 reuse the 64B line)
//  - 4 wave-coalesced 4B stores per chunk (lanes are consecutive y)
// Branch-free zero fill for empty cells (cndmask, no wave divergence).
// ---------------------------------------------------------------------------
__global__ void k_gather_out(const float4* __restrict__ feats4,
                             const int* __restrict__ idx,
                             float* __restrict__ out) {
    int bx = blockIdx.x;          // 0 .. B*X-1
    int y  = threadIdx.x;         // 0 .. 255
    int b  = bx >> 8;
    int x  = bx & 255;

    int row = idx[bx * YY + y];   // coalesced 4B read, L2-resident (1 MiB)
    bool valid = (row >= 0);
    const float4* fr = feats4 + (size_t)(valid ? row : 0) * (CC / 4);

    float* outp = out + ((size_t)b * CC * XX + x) * YY + y;

    #pragma unroll 4
    for (int c4 = 0; c4 < CC / 4; ++c4) {
        float4 v = fr[c4];                 // 16B gather; 4 consecutive c4 share a line
        if (!valid) { v.x = 0.f; v.y = 0.f; v.z = 0.f; v.w = 0.f; }
        int o = (c4 * 4) * (XX * YY);      // fits in int32 (< 2^26)
        outp[o]               = v.x;       // each store: 64 lanes x 4B contiguous in y
        outp[o + XX * YY]     = v.y;
        outp[o + 2 * XX * YY] = v.z;
        outp[o + 3 * XX * YY] = v.w;
    }
}

extern "C" void kernel_launch(void* const* d_in, const int* in_sizes, int n_in,
                              void* d_out, int out_size, void* d_ws, size_t ws_size,
                              hipStream_t stream) {
    const float* feats  = (const float*)d_in[0];   // [N, 256] fp32
    const int*   coords = (const int*)d_in[1];     // [N, 3]   int32
    int n = in_sizes[1] / 3;                       // N = 200000

    int*   idx   = (int*)d_ws;                     // 1 MiB scratch (re-poisoned each call)
    float* out   = (float*)d_out;

    // 1) idx = -1 everywhere (65536 int4 elements)
    k_fill_idx<<<NCELLS / 4 / 256, 256, 0, stream>>>((int4*)idx);

    // 2) scatter row ids into occupied cells
    k_scatter_idx<<<(n + 255) / 256, 256, 0, stream>>>(coords, idx, n);

    // 3) write every output element exactly once (feature value or 0)
    k_gather_out<<<BB * XX, 256, 0, stream>>>((const float4*)feats, idx, out);
}